// Round 3
// baseline (481.089 us; speedup 1.0000x reference)
//
#include <hip/hip_runtime.h>

// CoreSageLayer: x1 = (adj @ x)/deg ; out[k] = [x1|x] @ W[k] + bias, k=0..2
// N=8192, F=256, OUT=256. adj int32 in {0,1} (256 MB = the HBM floor).
//
// R3 vs R2 (435 us, unchanged from R1 -> fixed harness cost suspected):
//  - phase1 v3: full-K per block (no 32 MB partial round-trip, no reduce
//    kernel). 256 blocks x 1024 thr: 2 in-block K-groups x 8 waves
//    (4 n-strips x 2 m-frags). Single-barrier double-buffered LDS adj tile,
//    depth-2 register prefetch pipeline. deg fused into staging. Epilogue
//    combines the 2 K-group partials in LDS, normalizes, packs bf16 straight
//    into the phase-2 A-fragment layout.
//  - 3 dispatches total: prep, phase1, phase2.

typedef unsigned short u16;
typedef int      i32x4 __attribute__((ext_vector_type(4)));
typedef unsigned u32x2 __attribute__((ext_vector_type(2)));
typedef unsigned u32x4 __attribute__((ext_vector_type(4)));
typedef float    f32x4 __attribute__((ext_vector_type(4)));

__device__ __forceinline__ u16 f2b(float f) {  // fp32 -> bf16 RNE
  unsigned u = __builtin_bit_cast(unsigned, f);
  return (u16)((u + 0x7FFFu + ((u >> 16) & 1u)) >> 16);
}
__device__ __forceinline__ unsigned pack2(float a, float b) {
  return (unsigned)f2b(a) | ((unsigned)f2b(b) << 16);
}
__device__ __forceinline__ f32x4 mfma16(u32x4 a, u32x4 b, f32x4 c) {
  // D = A(16x32)*B(32x16)+C bf16. A/B: lane holds row/col l&15, k=(l>>4)*8+j.
  // C/D: col=l&15, row=(l>>4)*4+reg.
  asm("v_mfma_f32_16x16x32_bf16 %0, %1, %2, %0" : "+v"(c) : "v"(a), "v"(b));
  return c;
}

// ---- prep (one dispatch):
// blocks [0,1024):    xtf  = x bf16, frag-major (k=node, n=feature). 4 MB.
// blocks [1024,2048): nxtf upper half = x bf16 frag-major (k=feat 256..511).
// blocks [2048,2240): wtf  = weight bf16 frag-major (k=feat, n=768 cols). 768 KB.
__global__ __launch_bounds__(256) void prep(const float* __restrict__ x,
                                            const float* __restrict__ wgt,
                                            u16* __restrict__ xtf,
                                            u16* __restrict__ nxtf,
                                            u16* __restrict__ wtf) {
  const int b = blockIdx.x, t = threadIdx.x;
  if (b < 1024) {
    int c = b * 256 + t, kc8 = c >> 8, f = c & 255;
    const float* p = x + (size_t)kc8 * 2048 + f;
    u32x4 h;
    h.x = pack2(p[0],    p[256]);  h.y = pack2(p[512],  p[768]);
    h.z = pack2(p[1024], p[1280]); h.w = pack2(p[1536], p[1792]);
    *(u32x4*)(xtf + (size_t)c * 8) = h;
  } else if (b < 2048) {
    int c = (b - 1024) * 256 + t, kc8r = c >> 13, m = c & 8191;
    const float* p = x + (size_t)m * 256 + kc8r * 8;
    f32x4 p0 = *(const f32x4*)p, p1 = *(const f32x4*)(p + 4);
    u32x4 h;
    h.x = pack2(p0.x, p0.y); h.y = pack2(p0.z, p0.w);
    h.z = pack2(p1.x, p1.y); h.w = pack2(p1.z, p1.w);
    *(u32x4*)(nxtf + ((size_t)(32 + kc8r) * 8192 + m) * 8) = h;
  } else {
    int idx = b - 2048, kc8 = idx / 3, c = (idx % 3) * 256 + t;
    int kk = c >> 8, o = c & 255;
    const float* p = wgt + (size_t)kk * 131072 + (size_t)kc8 * 2048 + o;
    u32x4 h;
    h.x = pack2(p[0],    p[256]);  h.y = pack2(p[512],  p[768]);
    h.z = pack2(p[1024], p[1280]); h.w = pack2(p[1536], p[1792]);
    *(u32x4*)(wtf + ((size_t)kc8 * 768 + c) * 8) = h;
  }
}

// ---- phase 1 v3: x1 = (adj[m0:m0+32, :] @ x) / deg -> nxtf lower half.
// 256 blocks x 1024 thr. kg = t>>9 (in-block K-split: K half 4096), within
// group 8 waves = (m-frag mf = wg>>2) x (n-strip ns = wg&3, 64 cols).
// 64 steps of K=64 per group. LDS dbuf adj tile 32x64 per group, one
// barrier/step, depth-2 register prefetch. deg accumulated during staging.
__global__ __launch_bounds__(1024) void phase1(const int* __restrict__ adj,
                                               const u16* __restrict__ xtf,
                                               u16* __restrict__ nxtf) {
  __shared__ __align__(16) u16 As[2][2][32 * 72];  // [kg][buf][row][64k + 8 pad]
  __shared__ float Csum[32 * 260];
  __shared__ int   degs[1024];
  __shared__ float degrow[32];

  const int t = threadIdx.x, l = t & 63;
  const int kg = t >> 9, tg = t & 511;
  const int wg = tg >> 6;                 // wave in group: 0..7
  const int mf = wg >> 2, ns = wg & 3;    // m-frag, n-strip
  const int l15 = l & 15, l16 = l >> 4;
  const int m0 = blockIdx.x * 32;
  const int r = tg >> 4, q = tg & 15;     // staging: row 0..31, col-quad 0..15

  f32x4 acc[4] = {};
  int dsum = 0;

  const int* arow = adj + (size_t)(m0 + r) * 8192 + kg * 4096 + q * 4;
  u16* lds_w = &As[kg][0][r * 72 + q * 4];
  const u16* lds_a = &As[kg][0][(mf * 16 + l15) * 72 + l16 * 8];
  // B frag base: k = kg*4096 + step*64 + kc*32 + l16*8 -> chunk = (k>>3)*256 + f
  const u16* bbase = xtf + ((size_t)(kg * 512 + l16) * 256 + ns * 64 + l15) * 8;

  i32x4 pipe0 = __builtin_nontemporal_load((const i32x4*)arow);
  i32x4 pipe1 = __builtin_nontemporal_load((const i32x4*)(arow + 64));

  for (int step = 0; step < 64; ++step) {
    i32x4 p = pipe0;
    pipe0 = pipe1;
    if (step < 62)
      pipe1 = __builtin_nontemporal_load((const i32x4*)(arow + (step + 2) * 64));
    dsum += p.x + p.y + p.z + p.w;
    u32x2 h;
    h.x = (p.x ? 0x3F80u : 0u) | (p.y ? 0x3F800000u : 0u);
    h.y = (p.z ? 0x3F80u : 0u) | (p.w ? 0x3F800000u : 0u);
    *(u32x2*)(lds_w + (size_t)(step & 1) * 2304) = h;
    __syncthreads();
    // single-barrier dbuf is safe: reads of buf[(s+1)&1] (issued at step s-1)
    // retired before that wave's barrier(s) (compiler waitcnt before s_barrier).
    const u16* as_ = lds_a + (size_t)(step & 1) * 2304;
    const u16* bs  = bbase + (size_t)step * 16384;
#pragma unroll
    for (int kc = 0; kc < 2; ++kc) {
      u32x4 a = *(const u32x4*)(as_ + kc * 32);
#pragma unroll
      for (int nt = 0; nt < 4; ++nt) {
        u32x4 bfr = *(const u32x4*)(bs + (size_t)kc * 8192 + nt * 128);
        acc[nt] = mfma16(a, bfr, acc[nt]);
      }
    }
  }
  asm volatile("s_nop 7\n\ts_nop 7\n\ts_nop 7");  // MFMA D -> VALU read hazard

  degs[t] = dsum;
  __syncthreads();
  if (t < 32) {        // row t: sum both K-groups' 16 col-quad threads
    int s = 0;
#pragma unroll
    for (int kgg = 0; kgg < 2; ++kgg)
#pragma unroll
      for (int j = 0; j < 16; ++j) s += degs[kgg * 512 + t * 16 + j];
    degrow[t] = (float)s;
  }
  // combine the 2 K-groups' partial C tiles
#pragma unroll
  for (int round = 0; round < 2; ++round) {
    if (kg == round) {
#pragma unroll
      for (int nt = 0; nt < 4; ++nt)
#pragma unroll
        for (int i = 0; i < 4; ++i) {
          int row = mf * 16 + l16 * 4 + i;
          int col = ns * 64 + nt * 16 + l15;
          if (round == 0) Csum[row * 260 + col]  = acc[nt][i];
          else            Csum[row * 260 + col] += acc[nt][i];
        }
    }
    __syncthreads();
  }
  // x1 = S/deg -> nxtf (k<256 half), frag-major chunk = (f>>3)*8192 + m
  {
    int rr = t & 31, kc8 = t >> 5;  // 32 rows x 32 feature-octets
    float rd = 1.0f / degrow[rr];
    const float* cp = &Csum[rr * 260 + kc8 * 8];
    u32x4 h;
    h.x = pack2(cp[0] * rd, cp[1] * rd);
    h.y = pack2(cp[2] * rd, cp[3] * rd);
    h.z = pack2(cp[4] * rd, cp[5] * rd);
    h.w = pack2(cp[6] * rd, cp[7] * rd);
    *(u32x4*)(nxtf + ((size_t)kc8 * 8192 + m0 + rr) * 8) = h;
  }
}

// ---- phase 2: out[m, c=kk*256+o] = sum_k nx[m][k]*w_tf[c][k] + bias[o]
// M=8192 K=512 N=768. Zero LDS; both operands are ready frags in global.
// Grid (64,16): M-tile 128, N-tile 48; wave w owns rows w*32..w*32+31.
__global__ __launch_bounds__(256) void phase2(const u16* __restrict__ nxtf,
                                              const u16* __restrict__ wtf,
                                              const float* __restrict__ bias,
                                              float* __restrict__ out) {
  const int t = threadIdx.x, l = t & 63, w = t >> 6;
  const int l15 = l & 15, l16 = l >> 4;
  const int m0 = blockIdx.x * 128, c0 = blockIdx.y * 48;
  f32x4 acc[2][3] = {};
  const u16* abase = nxtf + (size_t)l16 * 65536 + (size_t)(m0 + w * 32 + l15) * 8;
  const u16* bbase = wtf  + (size_t)l16 * 6144  + (size_t)(c0 + l15) * 8;
  float bv[3];
#pragma unroll
  for (int nt = 0; nt < 3; ++nt) bv[nt] = bias[(c0 + nt * 16 + l15) & 255];
#pragma unroll 2
  for (int step = 0; step < 16; ++step) {        // K: 32 per step
    u32x4 a[2], b[3];
    a[0] = *(const u32x4*)(abase + (size_t)step * 262144);
    a[1] = *(const u32x4*)(abase + (size_t)step * 262144 + 128);
#pragma unroll
    for (int nt = 0; nt < 3; ++nt)
      b[nt] = *(const u32x4*)(bbase + (size_t)step * 24576 + nt * 128);
#pragma unroll
    for (int mt2 = 0; mt2 < 2; ++mt2)
#pragma unroll
      for (int nt = 0; nt < 3; ++nt)
        acc[mt2][nt] = mfma16(a[mt2], b[nt], acc[mt2][nt]);
  }
  asm volatile("s_nop 7\n\ts_nop 7\n\ts_nop 7");
#pragma unroll
  for (int mt2 = 0; mt2 < 2; ++mt2)
#pragma unroll
    for (int nt = 0; nt < 3; ++nt) {
      int c = c0 + nt * 16 + l15;
      int kk = c >> 8, o = c & 255;
      float* op = out + (size_t)kk * 2097152 +
                  (size_t)(m0 + w * 32 + mt2 * 16 + l16 * 4) * 256 + o;
#pragma unroll
      for (int i = 0; i < 4; ++i)
        __builtin_nontemporal_store(acc[mt2][nt][i] + bv[nt], op + (size_t)i * 256);
    }
}

extern "C" void kernel_launch(void* const* d_in, const int* in_sizes, int n_in,
                              void* d_out, int out_size, void* d_ws, size_t ws_size,
                              hipStream_t stream) {
  (void)in_sizes; (void)n_in; (void)out_size; (void)ws_size;
  const float* x    = (const float*)d_in[1];
  const int*   adj  = (const int*)d_in[2];
  const float* wgt  = (const float*)d_in[3];
  const float* bias = (const float*)d_in[4];
  float* out = (float*)d_out;

  char* ws = (char*)d_ws;
  u16* xtf  = (u16*)ws;                       // 4 MB
  u16* nxtf = (u16*)(ws + (4ull  << 20));     // 8 MB
  u16* wtf  = (u16*)(ws + (12ull << 20));     // 768 KB

  prep  <<<2240, 256, 0, stream>>>(x, wgt, xtf, nxtf, wtf);
  phase1<<<256, 1024, 0, stream>>>(adj, xtf, nxtf);
  phase2<<<dim3(64, 16), 256, 0, stream>>>(nxtf, wtf, bias, out);
}